// Round 5
// baseline (312.834 us; speedup 1.0000x reference)
//
#include <hip/hip_runtime.h>
#include <cmath>

#define NN 50000
#define KK 15
#define DD 128
#define HH 64
#define NKE (NN * KK)

#define TP_ROWS 64
#define TP_STRIDE 129   // odd dword stride: LDS bank = (lane + k) % 32 -> max 2-way (free)

// ---------------------------------------------------------------------------
// kP (R5 rewrite): LDS-staged row-per-lane GEMM.
//   ws[seg][row][j] = x[row] @ {ew1[0:128] | ew1[128:256] | dw1[0:128]}
// Old structure (~97 us) read x via wave-uniform SCALAR loads -> every load a
// K$ miss on streamed data (25.6 MB through 16 KB K$), serialized SMEM path.
// New: stage a 64-row x tile into LDS with coalesced vector loads; each lane
// owns one row (ds_read_b32, bank-conflict-free via stride 129); weights stay
// WAVE-UNIFORM (s_load scalar path — the session-proven invariant).
// 6 waves/block: wave w -> seg w>>1, j-half w&1, acc[32]/lane.
// ---------------------------------------------------------------------------
__global__ __launch_bounds__(384, 2) void kP(const float* __restrict__ x,
                                             const float* __restrict__ ew1,
                                             const float* __restrict__ dw1,
                                             float* __restrict__ ws) {
    __shared__ float xt[TP_ROWS * TP_STRIDE];   // 33,024 B
    int t = threadIdx.x;
    int lane = t & 63;
    int w = __builtin_amdgcn_readfirstlane(t >> 6);   // 0..5
    int seg = w >> 1;            // 0..2  (XA, XB, XC)
    int jh  = w & 1;             // 0..1  (j-half)
    int row0 = blockIdx.x * TP_ROWS;

    // ---- stage x tile: coalesced float4 global loads, b32 LDS writes ----
    for (int i = t; i < TP_ROWS * DD / 4; i += 384) {
        int r = (i * 4) / DD;
        int c = (i * 4) % DD;
        float4 v = make_float4(0.f, 0.f, 0.f, 0.f);
        if (row0 + r < NN) v = *(const float4*)(x + (size_t)(row0 + r) * DD + c);
        float* p = &xt[r * TP_STRIDE + c];
        p[0] = v.x; p[1] = v.y; p[2] = v.z; p[3] = v.w;
    }
    __syncthreads();

    // wave-uniform weight base: virtual row k lives at Wb + k*HH (+ jh*32)
    const float* Wb = (seg == 0) ? (ew1 + jh * 32)
                    : (seg == 1) ? (ew1 + (size_t)DD * HH + jh * 32)
                                 : (dw1 + jh * 32);

    float acc[32];
#pragma unroll
    for (int j = 0; j < 32; ++j) acc[j] = 0.f;

    const float* xrow = &xt[lane * TP_STRIDE];
#pragma unroll 1
    for (int k = 0; k < DD; ++k) {
        float xv = xrow[k];                         // per-lane LDS, 2-way max
        const float* wr = Wb + (size_t)k * HH;      // wave-uniform -> s_load
#pragma unroll
        for (int j4 = 0; j4 < 8; ++j4) {
            float4 wv = *(const float4*)(wr + j4 * 4);
            acc[j4 * 4 + 0] = fmaf(xv, wv.x, acc[j4 * 4 + 0]);
            acc[j4 * 4 + 1] = fmaf(xv, wv.y, acc[j4 * 4 + 1]);
            acc[j4 * 4 + 2] = fmaf(xv, wv.z, acc[j4 * 4 + 2]);
            acc[j4 * 4 + 3] = fmaf(xv, wv.w, acc[j4 * 4 + 3]);
        }
    }

    int myrow = row0 + lane;
    if (myrow < NN) {
        float* o = ws + (size_t)seg * NN * HH + (size_t)myrow * HH + jh * 32;
#pragma unroll
        for (int j4 = 0; j4 < 8; ++j4)
            *(float4*)(o + j4 * 4) = make_float4(acc[j4 * 4 + 0], acc[j4 * 4 + 1],
                                                 acc[j4 * 4 + 2], acc[j4 * 4 + 3]);
    }
}

// ---------------------------------------------------------------------------
// kE: thread-per-edge (EXACT R0 version — measured 93 us, VALUBusy 58%).
// acc[64] AGPR-backed, ew2 rows WAVE-UNIFORM -> s_load scalar path.
// R1/R2 falsified lane-split j (per-lane VMEM weights -> 8% VALUBusy);
// R4 falsified wave-split j (occupancy 68% but 117 us: VALU work constant,
// layer-1 duplicated, same s_load stall pattern in every wave).
// ---------------------------------------------------------------------------
__global__ __launch_bounds__(128, 4) void kE(const int* __restrict__ srcIdx,
                                             const float* __restrict__ dist,
                                             const float* __restrict__ ws,
                                             const float* __restrict__ ew1,
                                             const float* __restrict__ eb1,
                                             const float* __restrict__ ew2,
                                             const float* __restrict__ eb2,
                                             const float* __restrict__ ew3,
                                             const float* __restrict__ eb3,
                                             float* __restrict__ energy_out) {
    int e = blockIdx.x * 128 + threadIdx.x;
    if (e >= NKE) return;
    int s = srcIdx[e];
    int d = e / KK;
    float dd = dist[e];
    const float* A = ws + (size_t)d * HH;
    const float* B = ws + (size_t)NN * HH + (size_t)s * HH;
    const float* w1l = ew1 + 2 * DD * HH;

    float acc[HH];
#pragma unroll
    for (int j = 0; j < HH; ++j) acc[j] = 0.f;

    float4 a4 = *(const float4*)A;
    float4 b4 = *(const float4*)B;
#pragma unroll 1
    for (int i4 = 0; i4 < HH / 4; ++i4) {
        float4 a = a4, b = b4;
        int nx = (i4 + 1 < HH / 4) ? (i4 + 1) : i4;
        a4 = *(const float4*)(A + nx * 4);
        b4 = *(const float4*)(B + nx * 4);
        float h[4];
        h[0] = fmaxf(a.x + b.x + dd * w1l[i4 * 4 + 0] + eb1[i4 * 4 + 0], 0.f);
        h[1] = fmaxf(a.y + b.y + dd * w1l[i4 * 4 + 1] + eb1[i4 * 4 + 1], 0.f);
        h[2] = fmaxf(a.z + b.z + dd * w1l[i4 * 4 + 2] + eb1[i4 * 4 + 2], 0.f);
        h[3] = fmaxf(a.w + b.w + dd * w1l[i4 * 4 + 3] + eb1[i4 * 4 + 3], 0.f);
#pragma unroll
        for (int k = 0; k < 4; ++k) {
            const float* wr = ew2 + (i4 * 4 + k) * HH;   // wave-uniform!
#pragma unroll
            for (int j4 = 0; j4 < 16; ++j4) {
                float4 w = *(const float4*)(wr + j4 * 4);
                acc[j4 * 4 + 0] = fmaf(h[k], w.x, acc[j4 * 4 + 0]);
                acc[j4 * 4 + 1] = fmaf(h[k], w.y, acc[j4 * 4 + 1]);
                acc[j4 * 4 + 2] = fmaf(h[k], w.z, acc[j4 * 4 + 2]);
                acc[j4 * 4 + 3] = fmaf(h[k], w.w, acc[j4 * 4 + 3]);
            }
        }
    }
    float lg = eb3[0];
#pragma unroll
    for (int j = 0; j < HH; ++j)
        lg = fmaf(fmaxf(acc[j] + eb2[j], 0.f), ew3[j], lg);
    energy_out[e] = 1.f / (1.f + expf(-2.f * lg));
}

// ---------------------------------------------------------------------------
// kF: WAVE-split j (R4 version, ~64 us — on par with R0 form but keeps the
// wave-uniform weight invariant and 12 waves/CU).  Block = 4 waves <-> 64
// nodes; wave wv owns j-columns [wv*16, wv*16+16); kraw reduced via 1KB LDS;
// sort duplicated per wave; scatter writes striped by rank&3 == wv.
// ---------------------------------------------------------------------------
__global__ __launch_bounds__(256, 2) void kF(const float* __restrict__ ws,
                                             const float* __restrict__ dw1,
                                             const float* __restrict__ db1,
                                             const float* __restrict__ dw2,
                                             const float* __restrict__ db2,
                                             const float* __restrict__ dw3,
                                             const float* __restrict__ db3,
                                             float* __restrict__ out) {
    int lane = threadIdx.x & 63;
    int wv = __builtin_amdgcn_readfirstlane((int)(threadIdx.x >> 6));  // 0..3
    int n = blockIdx.x * 64 + lane;
    __shared__ float kred[4][64];

    bool valid = n < NN;
    int nc = valid ? n : (NN - 1);             // clamp: no early return (barrier!)
    const float* energy = out + 2 * (size_t)NKE;

    float ev[KK];
    float dh = 0.f;
#pragma unroll
    for (int j = 0; j < KK; ++j) {
        ev[j] = energy[(size_t)nc * KK + j];
        dh += ev[j];
    }

    const float* XC  = ws + 2 * (size_t)NN * HH + (size_t)nc * HH;
    const float* w1l = dw1 + DD * HH;
    const float* W2  = dw2 + wv * 16;          // wave-uniform col slice
    const float* db2s = db2 + wv * 16;
    const float* dw3s = dw3 + wv * 16;

    float acc[16];
#pragma unroll
    for (int j = 0; j < 16; ++j) acc[j] = 0.f;

    float4 c4 = *(const float4*)XC;
#pragma unroll 1
    for (int i4 = 0; i4 < HH / 4; ++i4) {
        float4 c = c4;
        int nx = (i4 + 1 < HH / 4) ? (i4 + 1) : i4;
        c4 = *(const float4*)(XC + nx * 4);
        float cv[4] = {c.x, c.y, c.z, c.w};
#pragma unroll
        for (int m = 0; m < 4; ++m) {
            int k = i4 * 4 + m;
            float g = fmaxf(cv[m] + dh * w1l[k] + db1[k], 0.f);
            const float* wr = W2 + k * HH;     // wave-uniform row
#pragma unroll
            for (int j4 = 0; j4 < 4; ++j4) {
                float4 w = *(const float4*)(wr + j4 * 4);
                acc[j4 * 4 + 0] = fmaf(g, w.x, acc[j4 * 4 + 0]);
                acc[j4 * 4 + 1] = fmaf(g, w.y, acc[j4 * 4 + 1]);
                acc[j4 * 4 + 2] = fmaf(g, w.z, acc[j4 * 4 + 2]);
                acc[j4 * 4 + 3] = fmaf(g, w.w, acc[j4 * 4 + 3]);
            }
        }
    }
    float kp_ = 0.f;
#pragma unroll
    for (int j = 0; j < 16; ++j)
        kp_ = fmaf(fmaxf(acc[j] + db2s[j], 0.f), dw3s[j], kp_);

    kred[wv][lane] = kp_;
    __syncthreads();
    float kraw = kred[0][lane] + kred[1][lane] + kred[2][lane] + kred[3][lane]
               + db3[0];
    if (!valid) return;

    float kcont = 2.f + 13.f / (1.f + expf(-kraw));
    if (wv == 3) out[3 * (size_t)NKE + n] = kcont;

    // register-resident sort of (energy desc, idx asc), 16-wide network
    float se[16];
    int si[16];
#pragma unroll
    for (int j = 0; j < KK; ++j) { se[j] = ev[j]; si[j] = j; }
    se[15] = -1.f; si[15] = 15;

#pragma unroll
    for (int pp = 1; pp < 16; pp <<= 1) {
#pragma unroll
        for (int k = pp; k >= 1; k >>= 1) {
#pragma unroll
            for (int j = k & (pp - 1); j + k < 16; j += 2 * k) {
#pragma unroll
                for (int i = 0; i < k; ++i) {
                    int a = i + j, b = i + j + k;
                    if (b < 16 && (a / (2 * pp)) == (b / (2 * pp))) {
                        bool sw = (se[b] > se[a]) ||
                                  (se[b] == se[a] && si[b] < si[a]);
                        float ea = sw ? se[b] : se[a];
                        float eb = sw ? se[a] : se[b];
                        int ia = sw ? si[b] : si[a];
                        int ib = sw ? si[a] : si[b];
                        se[a] = ea; se[b] = eb; si[a] = ia; si[b] = ib;
                    }
                }
            }
        }
    }

    float kint = rintf(kcont);
    kint = fminf(fmaxf(kint, 2.f), 15.f);

    float wsrt[KK];
    float denom = 0.f;
#pragma unroll
    for (int r = 0; r < KK; ++r) {
        float sel = ((float)(r + 1) <= kint) ? 1.f : 0.f;
        float wvv = se[r] * sel;
        wsrt[r] = wvv;
        denom += wvv;
    }
    denom = fmaxf(denom, 1e-12f);

#pragma unroll
    for (int r = 0; r < KK; ++r) {
        if ((r & 3) == wv) {                   // stripe writes across the 4 waves
            float sel = ((float)(r + 1) <= kint) ? 1.f : 0.f;
            int j0 = si[r];
            out[(size_t)NKE + (size_t)n * KK + j0] = sel;     // edge_gate
            out[(size_t)n * KK + j0] = wsrt[r] / denom;       // edge_weight
        }
    }
}

extern "C" void kernel_launch(void* const* d_in, const int* in_sizes, int n_in,
                              void* d_out, int out_size, void* d_ws, size_t ws_size,
                              hipStream_t stream) {
    const float* x   = (const float*)d_in[0];
    const int*   ei  = (const int*)d_in[1];
    const float* ed  = (const float*)d_in[2];
    const float* ew1 = (const float*)d_in[3];
    const float* eb1 = (const float*)d_in[4];
    const float* ew2 = (const float*)d_in[5];
    const float* eb2 = (const float*)d_in[6];
    const float* ew3 = (const float*)d_in[7];
    const float* eb3 = (const float*)d_in[8];
    const float* dw1 = (const float*)d_in[9];
    const float* db1 = (const float*)d_in[10];
    const float* dw2 = (const float*)d_in[11];
    const float* db2 = (const float*)d_in[12];
    const float* dw3 = (const float*)d_in[13];
    const float* db3 = (const float*)d_in[14];
    float* out = (float*)d_out;
    float* ws  = (float*)d_ws;

    hipLaunchKernelGGL(kP, dim3((NN + TP_ROWS - 1) / TP_ROWS), dim3(384), 0, stream,
                       x, ew1, dw1, ws);
    hipLaunchKernelGGL(kE, dim3((NKE + 127) / 128), dim3(128), 0, stream,
                       ei, ed, ws, ew1, eb1, ew2, eb2, ew3, eb3,
                       out + 2 * (size_t)NKE);
    hipLaunchKernelGGL(kF, dim3((NN + 63) / 64), dim3(256), 0, stream,
                       ws, dw1, db1, dw2, db2, dw3, db3, out);
}

// Round 6
// 294.066 us; speedup vs baseline: 1.0638x; 1.0638x over previous
//
#include <hip/hip_runtime.h>
#include <cmath>

#define NN 50000
#define KK 15
#define DD 128
#define HH 64
#define NKE (NN * KK)

#define TP_ROWS 64
#define TP_STRIDE 129   // odd dword stride: LDS bank = (lane + k) % 32 -> max 2-way (free)

// ---------------------------------------------------------------------------
// kP (R6): LDS-staged row-per-lane GEMM, k-loop in chunks of 8.
// R5 post-mortem: VALUBusy 16%, no spill, no traffic problem -> pure latency
// chain: unroll-1 forced one lgkmcnt(0) per k (1 ds_read + 2 s_load K$-miss
// ~300cy vs 64cy of FMA).  Chunked unroll makes 8 ds_reads + 16 s_loads
// co-outstanding -> latency amortized; SGPR pressure bounds in-flight weight
// rows at ~2-3, still 2-4x fewer stalls.
// Weights stay WAVE-UNIFORM (s_load path; session invariant).
// ---------------------------------------------------------------------------
__global__ __launch_bounds__(384, 2) void kP(const float* __restrict__ x,
                                             const float* __restrict__ ew1,
                                             const float* __restrict__ dw1,
                                             float* __restrict__ ws) {
    __shared__ float xt[TP_ROWS * TP_STRIDE];   // 33,024 B
    int t = threadIdx.x;
    int lane = t & 63;
    int w = __builtin_amdgcn_readfirstlane(t >> 6);   // 0..5
    int seg = w >> 1;            // 0..2  (XA, XB, XC)
    int jh  = w & 1;             // 0..1  (j-half)
    int row0 = blockIdx.x * TP_ROWS;

    // ---- stage x tile: coalesced float4 global loads, b32 LDS writes ----
    for (int i = t; i < TP_ROWS * DD / 4; i += 384) {
        int r = (i * 4) / DD;
        int c = (i * 4) % DD;
        float4 v = make_float4(0.f, 0.f, 0.f, 0.f);
        if (row0 + r < NN) v = *(const float4*)(x + (size_t)(row0 + r) * DD + c);
        float* p = &xt[r * TP_STRIDE + c];
        p[0] = v.x; p[1] = v.y; p[2] = v.z; p[3] = v.w;
    }
    __syncthreads();

    // wave-uniform weight base: virtual row k lives at Wb + k*HH (+ jh*32)
    const float* Wb = (seg == 0) ? (ew1 + jh * 32)
                    : (seg == 1) ? (ew1 + (size_t)DD * HH + jh * 32)
                                 : (dw1 + jh * 32);

    float acc[32];
#pragma unroll
    for (int j = 0; j < 32; ++j) acc[j] = 0.f;

    const float* xrow = &xt[lane * TP_STRIDE];
#pragma unroll 1
    for (int kc = 0; kc < DD; kc += 8) {
        // 8 LDS reads issued together (multiple outstanding, one wait)
        float xv[8];
#pragma unroll
        for (int u = 0; u < 8; ++u) xv[u] = xrow[kc + u];
        // 8 weight rows: 16 s_loads co-scheduled by the compiler across the
        // unrolled body (SGPR pressure permitting) -> miss latency amortized
#pragma unroll
        for (int u = 0; u < 8; ++u) {
            const float* wr = Wb + (size_t)(kc + u) * HH;   // wave-uniform
#pragma unroll
            for (int j4 = 0; j4 < 8; ++j4) {
                float4 wv = *(const float4*)(wr + j4 * 4);
                acc[j4 * 4 + 0] = fmaf(xv[u], wv.x, acc[j4 * 4 + 0]);
                acc[j4 * 4 + 1] = fmaf(xv[u], wv.y, acc[j4 * 4 + 1]);
                acc[j4 * 4 + 2] = fmaf(xv[u], wv.z, acc[j4 * 4 + 2]);
                acc[j4 * 4 + 3] = fmaf(xv[u], wv.w, acc[j4 * 4 + 3]);
            }
        }
    }

    int myrow = row0 + lane;
    if (myrow < NN) {
        float* o = ws + (size_t)seg * NN * HH + (size_t)myrow * HH + jh * 32;
#pragma unroll
        for (int j4 = 0; j4 < 8; ++j4)
            *(float4*)(o + j4 * 4) = make_float4(acc[j4 * 4 + 0], acc[j4 * 4 + 1],
                                                 acc[j4 * 4 + 2], acc[j4 * 4 + 3]);
    }
}

// ---------------------------------------------------------------------------
// kE: thread-per-edge (EXACT R0 version — measured 93 us, VALUBusy 58%).
// acc[64] AGPR-backed, ew2 rows WAVE-UNIFORM -> s_load scalar path.
// R1/R2 falsified lane-split j (per-lane VMEM weights -> 8% VALUBusy);
// R4 falsified wave-split j (occupancy 68% but 117 us: VALU work constant,
// layer-1 duplicated, same s_load stall pattern in every wave).
// ---------------------------------------------------------------------------
__global__ __launch_bounds__(128, 4) void kE(const int* __restrict__ srcIdx,
                                             const float* __restrict__ dist,
                                             const float* __restrict__ ws,
                                             const float* __restrict__ ew1,
                                             const float* __restrict__ eb1,
                                             const float* __restrict__ ew2,
                                             const float* __restrict__ eb2,
                                             const float* __restrict__ ew3,
                                             const float* __restrict__ eb3,
                                             float* __restrict__ energy_out) {
    int e = blockIdx.x * 128 + threadIdx.x;
    if (e >= NKE) return;
    int s = srcIdx[e];
    int d = e / KK;
    float dd = dist[e];
    const float* A = ws + (size_t)d * HH;
    const float* B = ws + (size_t)NN * HH + (size_t)s * HH;
    const float* w1l = ew1 + 2 * DD * HH;

    float acc[HH];
#pragma unroll
    for (int j = 0; j < HH; ++j) acc[j] = 0.f;

    float4 a4 = *(const float4*)A;
    float4 b4 = *(const float4*)B;
#pragma unroll 1
    for (int i4 = 0; i4 < HH / 4; ++i4) {
        float4 a = a4, b = b4;
        int nx = (i4 + 1 < HH / 4) ? (i4 + 1) : i4;
        a4 = *(const float4*)(A + nx * 4);
        b4 = *(const float4*)(B + nx * 4);
        float h[4];
        h[0] = fmaxf(a.x + b.x + dd * w1l[i4 * 4 + 0] + eb1[i4 * 4 + 0], 0.f);
        h[1] = fmaxf(a.y + b.y + dd * w1l[i4 * 4 + 1] + eb1[i4 * 4 + 1], 0.f);
        h[2] = fmaxf(a.z + b.z + dd * w1l[i4 * 4 + 2] + eb1[i4 * 4 + 2], 0.f);
        h[3] = fmaxf(a.w + b.w + dd * w1l[i4 * 4 + 3] + eb1[i4 * 4 + 3], 0.f);
#pragma unroll
        for (int k = 0; k < 4; ++k) {
            const float* wr = ew2 + (i4 * 4 + k) * HH;   // wave-uniform!
#pragma unroll
            for (int j4 = 0; j4 < 16; ++j4) {
                float4 w = *(const float4*)(wr + j4 * 4);
                acc[j4 * 4 + 0] = fmaf(h[k], w.x, acc[j4 * 4 + 0]);
                acc[j4 * 4 + 1] = fmaf(h[k], w.y, acc[j4 * 4 + 1]);
                acc[j4 * 4 + 2] = fmaf(h[k], w.z, acc[j4 * 4 + 2]);
                acc[j4 * 4 + 3] = fmaf(h[k], w.w, acc[j4 * 4 + 3]);
            }
        }
    }
    float lg = eb3[0];
#pragma unroll
    for (int j = 0; j < HH; ++j)
        lg = fmaf(fmaxf(acc[j] + eb2[j], 0.f), ew3[j], lg);
    energy_out[e] = 1.f / (1.f + expf(-2.f * lg));
}

// ---------------------------------------------------------------------------
// kF: WAVE-split j (R4 version, ~64 us).  Block = 4 waves <-> 64 nodes;
// wave wv owns j-columns [wv*16, wv*16+16) (wave-uniform weight slice);
// kraw reduced via 1KB LDS; sort duplicated per wave; writes striped.
// ---------------------------------------------------------------------------
__global__ __launch_bounds__(256, 2) void kF(const float* __restrict__ ws,
                                             const float* __restrict__ dw1,
                                             const float* __restrict__ db1,
                                             const float* __restrict__ dw2,
                                             const float* __restrict__ db2,
                                             const float* __restrict__ dw3,
                                             const float* __restrict__ db3,
                                             float* __restrict__ out) {
    int lane = threadIdx.x & 63;
    int wv = __builtin_amdgcn_readfirstlane((int)(threadIdx.x >> 6));  // 0..3
    int n = blockIdx.x * 64 + lane;
    __shared__ float kred[4][64];

    bool valid = n < NN;
    int nc = valid ? n : (NN - 1);             // clamp: no early return (barrier!)
    const float* energy = out + 2 * (size_t)NKE;

    float ev[KK];
    float dh = 0.f;
#pragma unroll
    for (int j = 0; j < KK; ++j) {
        ev[j] = energy[(size_t)nc * KK + j];
        dh += ev[j];
    }

    const float* XC  = ws + 2 * (size_t)NN * HH + (size_t)nc * HH;
    const float* w1l = dw1 + DD * HH;
    const float* W2  = dw2 + wv * 16;          // wave-uniform col slice
    const float* db2s = db2 + wv * 16;
    const float* dw3s = dw3 + wv * 16;

    float acc[16];
#pragma unroll
    for (int j = 0; j < 16; ++j) acc[j] = 0.f;

    float4 c4 = *(const float4*)XC;
#pragma unroll 1
    for (int i4 = 0; i4 < HH / 4; ++i4) {
        float4 c = c4;
        int nx = (i4 + 1 < HH / 4) ? (i4 + 1) : i4;
        c4 = *(const float4*)(XC + nx * 4);
        float cv[4] = {c.x, c.y, c.z, c.w};
#pragma unroll
        for (int m = 0; m < 4; ++m) {
            int k = i4 * 4 + m;
            float g = fmaxf(cv[m] + dh * w1l[k] + db1[k], 0.f);
            const float* wr = W2 + k * HH;     // wave-uniform row
#pragma unroll
            for (int j4 = 0; j4 < 4; ++j4) {
                float4 w = *(const float4*)(wr + j4 * 4);
                acc[j4 * 4 + 0] = fmaf(g, w.x, acc[j4 * 4 + 0]);
                acc[j4 * 4 + 1] = fmaf(g, w.y, acc[j4 * 4 + 1]);
                acc[j4 * 4 + 2] = fmaf(g, w.z, acc[j4 * 4 + 2]);
                acc[j4 * 4 + 3] = fmaf(g, w.w, acc[j4 * 4 + 3]);
            }
        }
    }
    float kp_ = 0.f;
#pragma unroll
    for (int j = 0; j < 16; ++j)
        kp_ = fmaf(fmaxf(acc[j] + db2s[j], 0.f), dw3s[j], kp_);

    kred[wv][lane] = kp_;
    __syncthreads();
    float kraw = kred[0][lane] + kred[1][lane] + kred[2][lane] + kred[3][lane]
               + db3[0];
    if (!valid) return;

    float kcont = 2.f + 13.f / (1.f + expf(-kraw));
    if (wv == 3) out[3 * (size_t)NKE + n] = kcont;

    // register-resident sort of (energy desc, idx asc), 16-wide network
    float se[16];
    int si[16];
#pragma unroll
    for (int j = 0; j < KK; ++j) { se[j] = ev[j]; si[j] = j; }
    se[15] = -1.f; si[15] = 15;

#pragma unroll
    for (int pp = 1; pp < 16; pp <<= 1) {
#pragma unroll
        for (int k = pp; k >= 1; k >>= 1) {
#pragma unroll
            for (int j = k & (pp - 1); j + k < 16; j += 2 * k) {
#pragma unroll
                for (int i = 0; i < k; ++i) {
                    int a = i + j, b = i + j + k;
                    if (b < 16 && (a / (2 * pp)) == (b / (2 * pp))) {
                        bool sw = (se[b] > se[a]) ||
                                  (se[b] == se[a] && si[b] < si[a]);
                        float ea = sw ? se[b] : se[a];
                        float eb = sw ? se[a] : se[b];
                        int ia = sw ? si[b] : si[a];
                        int ib = sw ? si[a] : si[b];
                        se[a] = ea; se[b] = eb; si[a] = ia; si[b] = ib;
                    }
                }
            }
        }
    }

    float kint = rintf(kcont);
    kint = fminf(fmaxf(kint, 2.f), 15.f);

    float wsrt[KK];
    float denom = 0.f;
#pragma unroll
    for (int r = 0; r < KK; ++r) {
        float sel = ((float)(r + 1) <= kint) ? 1.f : 0.f;
        float wvv = se[r] * sel;
        wsrt[r] = wvv;
        denom += wvv;
    }
    denom = fmaxf(denom, 1e-12f);

#pragma unroll
    for (int r = 0; r < KK; ++r) {
        if ((r & 3) == wv) {                   // stripe writes across the 4 waves
            float sel = ((float)(r + 1) <= kint) ? 1.f : 0.f;
            int j0 = si[r];
            out[(size_t)NKE + (size_t)n * KK + j0] = sel;     // edge_gate
            out[(size_t)n * KK + j0] = wsrt[r] / denom;       // edge_weight
        }
    }
}

extern "C" void kernel_launch(void* const* d_in, const int* in_sizes, int n_in,
                              void* d_out, int out_size, void* d_ws, size_t ws_size,
                              hipStream_t stream) {
    const float* x   = (const float*)d_in[0];
    const int*   ei  = (const int*)d_in[1];
    const float* ed  = (const float*)d_in[2];
    const float* ew1 = (const float*)d_in[3];
    const float* eb1 = (const float*)d_in[4];
    const float* ew2 = (const float*)d_in[5];
    const float* eb2 = (const float*)d_in[6];
    const float* ew3 = (const float*)d_in[7];
    const float* eb3 = (const float*)d_in[8];
    const float* dw1 = (const float*)d_in[9];
    const float* db1 = (const float*)d_in[10];
    const float* dw2 = (const float*)d_in[11];
    const float* db2 = (const float*)d_in[12];
    const float* dw3 = (const float*)d_in[13];
    const float* db3 = (const float*)d_in[14];
    float* out = (float*)d_out;
    float* ws  = (float*)d_ws;

    hipLaunchKernelGGL(kP, dim3((NN + TP_ROWS - 1) / TP_ROWS), dim3(384), 0, stream,
                       x, ew1, dw1, ws);
    hipLaunchKernelGGL(kE, dim3((NKE + 127) / 128), dim3(128), 0, stream,
                       ei, ed, ws, ew1, eb1, ew2, eb2, ew3, eb3,
                       out + 2 * (size_t)NKE);
    hipLaunchKernelGGL(kF, dim3((NN + 63) / 64), dim3(256), 0, stream,
                       ws, dw1, db1, dw2, db2, dw3, db3, out);
}